// Round 2
// baseline (4638.112 us; speedup 1.0000x reference)
//
#include <hip/hip_runtime.h>
#include <hip/hip_bf16.h>

// Shapes (fixed): B=128, F=8, K=256, D=256, H=256, HFF=512, L=2, M_PREV=2
#define B_   128
#define F_   8
#define K_   256
#define D_   256
#define H_   256
#define HFF_ 512
#define RT   32   // k-rows per block in main kernel

// ---------------------------------------------------------------------------
// h0[k][j] = sum_i codebook[k][i] * W_in[i][j] + b_in[j]      (256x256)
__global__ void k_h0(const float* __restrict__ cb, const float* __restrict__ Win,
                     const float* __restrict__ bin, float* __restrict__ h0) {
  __shared__ float row[D_];
  const int k = blockIdx.x, j = threadIdx.x;
  row[j] = cb[k * D_ + j];
  __syncthreads();
  float acc = bin[j];
  #pragma unroll 4
  for (int i = 0; i < D_; ++i) acc = fmaf(row[i], Win[i * H_ + j], acc);
  h0[k * H_ + j] = acc;
}

// u[k][j] = sum_i h0[k][i]*Wcat[i][j]                 (blocks 0..255)
// v[bf][j] = b_cat[j] + sum_i xhat[bf][i]*Wcat[H+i][j] (blocks 256..1279)
__global__ void k_uv(const float* __restrict__ h0, const float* __restrict__ Wcat,
                     const float* __restrict__ bcat, const float* __restrict__ xhat,
                     float* __restrict__ u, float* __restrict__ v) {
  __shared__ float row[D_];
  const int blk = blockIdx.x, j = threadIdx.x;
  if (blk < K_) {
    row[j] = h0[blk * H_ + j];
    __syncthreads();
    float acc = 0.f;
    #pragma unroll 4
    for (int i = 0; i < H_; ++i) acc = fmaf(row[i], Wcat[i * H_ + j], acc);
    u[blk * H_ + j] = acc;
  } else {
    const int bf = blk - K_;
    row[j] = xhat[bf * D_ + j];
    __syncthreads();
    float acc = bcat[j];
    #pragma unroll 4
    for (int i = 0; i < D_; ++i) acc = fmaf(row[i], Wcat[(H_ + i) * H_ + j], acc);
    v[bf * H_ + j] = acc;
  }
}

// ---------------------------------------------------------------------------
// Main fused kernel: per block = one (b,f) pair x 32 k's.
// h kept transposed in LDS: hT[i][r]  (stride 36 -> conflict-free b128 reads).
// Thread grid: 256 = 32 tcol x 8 trow. Per-thread tiles: 4 rows x {4,8} cols.
__global__ __launch_bounds__(256, 2) void k_main(
    const float* __restrict__ u, const float* __restrict__ v,
    const float* __restrict__ W1, const float* __restrict__ b1,
    const float* __restrict__ W2, const float* __restrict__ b2,
    const float* __restrict__ Wout, const float* __restrict__ bout,
    const float* __restrict__ cb, const float* __restrict__ xhat,
    const float* __restrict__ x, float* __restrict__ dists) {
  __shared__ float hT[H_][RT + 4];     // [feature i][row r], 36.9 KB
  __shared__ float hmT[128][RT + 4];   // relu chunk transposed, 18.4 KB
  __shared__ float x_s[D_];
  __shared__ float xh_s[D_];

  const int t   = threadIdx.x;
  const int blk = blockIdx.x;
  const int bf  = blk >> 3;            // (b,f) pair
  const int k0  = (blk & 7) << 5;      // k tile base
  const int b   = bf >> 3;
  const int f   = bf & 7;
  const int tcol = t & 31;
  const int trow = t >> 5;
  const int r4   = trow << 2;          // this thread's row base (0..28)

  x_s[t]  = x[b * D_ + t];
  xh_s[t] = xhat[bf * D_ + t];
  {
    const float vreg = v[bf * H_ + t];
    #pragma unroll
    for (int r = 0; r < RT; ++r)
      hT[t][r] = u[(k0 + r) * H_ + t] + vreg;
  }
  __syncthreads();

  for (int l = 0; l < 2; ++l) {
    const float* __restrict__ W1l = W1 + l * (H_ * HFF_);
    const float* __restrict__ b1l = b1 + l * HFF_;
    const float* __restrict__ W2l = W2 + l * (HFF_ * H_);
    const float* __restrict__ b2l = b2 + l * H_;

    float hacc[4][8];
    #pragma unroll
    for (int rr = 0; rr < 4; ++rr)
      #pragma unroll
      for (int cc = 0; cc < 8; ++cc) hacc[rr][cc] = 0.f;

    for (int ch = 0; ch < 4; ++ch) {
      // ---- GEMM1: hm = relu(h @ W1[:, ch*128 : ch*128+128] + b1) ----
      float acc1[4][4];
      #pragma unroll
      for (int rr = 0; rr < 4; ++rr)
        #pragma unroll
        for (int cc = 0; cc < 4; ++cc) acc1[rr][cc] = 0.f;

      const float* __restrict__ W1c = W1l + ch * 128 + tcol * 4;
      for (int i = 0; i < H_; i += 4) {
        float ha[4][4], wa[4][4];
        #pragma unroll
        for (int ii = 0; ii < 4; ++ii) {
          float4 hv = *(const float4*)&hT[i + ii][r4];
          ha[ii][0] = hv.x; ha[ii][1] = hv.y; ha[ii][2] = hv.z; ha[ii][3] = hv.w;
          float4 wv = *(const float4*)&W1c[(i + ii) * HFF_];
          wa[ii][0] = wv.x; wa[ii][1] = wv.y; wa[ii][2] = wv.z; wa[ii][3] = wv.w;
        }
        #pragma unroll
        for (int ii = 0; ii < 4; ++ii)
          #pragma unroll
          for (int rr = 0; rr < 4; ++rr)
            #pragma unroll
            for (int cc = 0; cc < 4; ++cc)
              acc1[rr][cc] = fmaf(ha[ii][rr], wa[ii][cc], acc1[rr][cc]);
      }
      // bias + relu, store transposed
      #pragma unroll
      for (int cc = 0; cc < 4; ++cc) {
        const float bb = b1l[ch * 128 + tcol * 4 + cc];
        float4 wv;
        wv.x = fmaxf(acc1[0][cc] + bb, 0.f);
        wv.y = fmaxf(acc1[1][cc] + bb, 0.f);
        wv.z = fmaxf(acc1[2][cc] + bb, 0.f);
        wv.w = fmaxf(acc1[3][cc] + bb, 0.f);
        *(float4*)&hmT[tcol * 4 + cc][r4] = wv;
      }
      __syncthreads();

      // ---- GEMM2: hacc += hm @ W2[ch*128 : ch*128+128, :] ----
      const float* __restrict__ W2c = W2l + (ch * 128) * H_ + tcol * 8;
      for (int jj = 0; jj < 128; jj += 4) {
        float hm[4][4];
        #pragma unroll
        for (int jjj = 0; jjj < 4; ++jjj) {
          float4 hv = *(const float4*)&hmT[jj + jjj][r4];
          hm[jjj][0] = hv.x; hm[jjj][1] = hv.y; hm[jjj][2] = hv.z; hm[jjj][3] = hv.w;
        }
        #pragma unroll
        for (int jjj = 0; jjj < 4; ++jjj) {
          float4 wA = *(const float4*)&W2c[(jj + jjj) * H_];
          float4 wB = *(const float4*)&W2c[(jj + jjj) * H_ + 4];
          float wr[8] = {wA.x, wA.y, wA.z, wA.w, wB.x, wB.y, wB.z, wB.w};
          #pragma unroll
          for (int rr = 0; rr < 4; ++rr)
            #pragma unroll
            for (int cc = 0; cc < 8; ++cc)
              hacc[rr][cc] = fmaf(hm[jjj][rr], wr[cc], hacc[rr][cc]);
        }
      }
      __syncthreads();
    }

    // ---- residual writeback: h += hacc + b2 ----
    #pragma unroll
    for (int cc = 0; cc < 8; ++cc) {
      const int c = tcol * 8 + cc;
      const float bb = b2l[c];
      float4 hv = *(float4*)&hT[c][r4];
      hv.x += hacc[0][cc] + bb;
      hv.y += hacc[1][cc] + bb;
      hv.z += hacc[2][cc] + bb;
      hv.w += hacc[3][cc] + bb;
      *(float4*)&hT[c][r4] = hv;
    }
    __syncthreads();
  }

  // ---- GEMM3: cw = h @ W_out + b_out + codebook[k] + xhat[b,f]; dist ----
  float acc3[4][8];
  #pragma unroll
  for (int rr = 0; rr < 4; ++rr)
    #pragma unroll
    for (int cc = 0; cc < 8; ++cc) acc3[rr][cc] = 0.f;

  const float* __restrict__ Woc = Wout + tcol * 8;
  for (int i = 0; i < H_; ++i) {
    float4 hv = *(const float4*)&hT[i][r4];
    float4 wA = *(const float4*)&Woc[i * D_];
    float4 wB = *(const float4*)&Woc[i * D_ + 4];
    float hr[4] = {hv.x, hv.y, hv.z, hv.w};
    float wr[8] = {wA.x, wA.y, wA.z, wA.w, wB.x, wB.y, wB.z, wB.w};
    #pragma unroll
    for (int rr = 0; rr < 4; ++rr)
      #pragma unroll
      for (int cc = 0; cc < 8; ++cc)
        acc3[rr][cc] = fmaf(hr[rr], wr[cc], acc3[rr][cc]);
  }

  float4 boA = *(const float4*)&bout[tcol * 8];
  float4 boB = *(const float4*)&bout[tcol * 8 + 4];
  float4 xA  = *(const float4*)&x_s[tcol * 8];
  float4 xB  = *(const float4*)&x_s[tcol * 8 + 4];
  float4 xhA = *(const float4*)&xh_s[tcol * 8];
  float4 xhB = *(const float4*)&xh_s[tcol * 8 + 4];
  float bo[8] = {boA.x, boA.y, boA.z, boA.w, boB.x, boB.y, boB.z, boB.w};
  float xv[8] = {xA.x, xA.y, xA.z, xA.w, xB.x, xB.y, xB.z, xB.w};
  float xh[8] = {xhA.x, xhA.y, xhA.z, xhA.w, xhB.x, xhB.y, xhB.z, xhB.w};

  float pd[4];
  #pragma unroll
  for (int rr = 0; rr < 4; ++rr) {
    const int k = k0 + r4 + rr;
    float4 cA = *(const float4*)&cb[k * D_ + tcol * 8];
    float4 cB = *(const float4*)&cb[k * D_ + tcol * 8 + 4];
    float cbv[8] = {cA.x, cA.y, cA.z, cA.w, cB.x, cB.y, cB.z, cB.w};
    float s = 0.f;
    #pragma unroll
    for (int cc = 0; cc < 8; ++cc) {
      const float cw = acc3[rr][cc] + bo[cc] + cbv[cc] + xh[cc];
      s += cw * (cw - 2.f * xv[cc]);   // ||x||^2 const per b, argmin-invariant
    }
    pd[rr] = s;
  }
  // reduce over the 32 tcol lanes (each 32-lane half of a wave = one trow)
  #pragma unroll
  for (int m = 1; m < 32; m <<= 1)
    #pragma unroll
    for (int rr = 0; rr < 4; ++rr)
      pd[rr] += __shfl_xor(pd[rr], m, 64);

  if (tcol == 0) {
    #pragma unroll
    for (int rr = 0; rr < 4; ++rr)
      dists[b * (F_ * K_) + f * K_ + k0 + r4 + rr] = pd[rr];
  }
}

// ---------------------------------------------------------------------------
__global__ void k_argmin(const float* __restrict__ dists, int* __restrict__ idxp) {
  __shared__ float bv[256];
  __shared__ int bi_s[256];
  const int b = blockIdx.x, t = threadIdx.x;
  float best = 3.4e38f;
  int bi = 0;
  for (int j = t; j < F_ * K_; j += 256) {
    const float dv = dists[b * (F_ * K_) + j];
    if (dv < best) { best = dv; bi = j; }   // ascending j -> keeps first min
  }
  bv[t] = best; bi_s[t] = bi;
  __syncthreads();
  for (int s = 128; s > 0; s >>= 1) {
    if (t < s) {
      const float ov = bv[t + s];
      const int oi = bi_s[t + s];
      if (ov < bv[t] || (ov == bv[t] && oi < bi_s[t])) { bv[t] = ov; bi_s[t] = oi; }
    }
    __syncthreads();
  }
  if (t == 0) idxp[b] = bi_s[0];
}

// ---------------------------------------------------------------------------
// Recompute only the winning row per batch; write FLOAT32 outputs.
// (d_out is float32: reference outputs are fp32/int64 -> "else float*" rule.
//  Round-1 failure signature |2048 - 1.664| = 2046.336 proved bf16 writes were
//  being read back as packed halves of float32 words.)
__global__ void k_finalize(const float* __restrict__ u, const float* __restrict__ v,
                           const float* __restrict__ W1, const float* __restrict__ b1,
                           const float* __restrict__ W2, const float* __restrict__ b2,
                           const float* __restrict__ Wout, const float* __restrict__ bout,
                           const float* __restrict__ cb, const float* __restrict__ xhat,
                           const int* __restrict__ codes, const int* __restrict__ idxp,
                           float* __restrict__ out) {
  __shared__ float hs[H_];
  __shared__ float hms[HFF_];
  const int b = blockIdx.x, t = threadIdx.x;
  const int idx = idxp[b];
  const int f = idx >> 8, k = idx & 255;
  const int bf = b * F_ + f;

  hs[t] = u[k * H_ + t] + v[bf * H_ + t];
  __syncthreads();

  for (int l = 0; l < 2; ++l) {
    const float* __restrict__ W1l = W1 + l * (H_ * HFF_);
    const float* __restrict__ W2l = W2 + l * (HFF_ * H_);
    float a0 = b1[l * HFF_ + t];
    float a1 = b1[l * HFF_ + 256 + t];
    for (int i = 0; i < H_; ++i) {
      const float hv = hs[i];
      a0 = fmaf(hv, W1l[i * HFF_ + t], a0);
      a1 = fmaf(hv, W1l[i * HFF_ + 256 + t], a1);
    }
    hms[t] = fmaxf(a0, 0.f);
    hms[t + 256] = fmaxf(a1, 0.f);
    __syncthreads();
    float hn = hs[t] + b2[l * H_ + t];
    for (int jj = 0; jj < HFF_; ++jj)
      hn = fmaf(hms[jj], W2l[jj * H_ + t], hn);
    __syncthreads();
    hs[t] = hn;
    __syncthreads();
  }

  float cw = bout[t] + cb[k * D_ + t] + xhat[bf * D_ + t];
  for (int i = 0; i < H_; ++i) cw = fmaf(hs[i], Wout[i * D_ + t], cw);

  out[b * D_ + t] = cw;                            // xhat_next (B,1,D) fp32
  if (t < 2)
    out[B_ * D_ + t * B_ + b] = (float)codes[t * B_ + b];
  else if (t == 2)
    out[B_ * D_ + 2 * B_ + b] = (float)idx;
}

// ---------------------------------------------------------------------------
extern "C" void kernel_launch(void* const* d_in, const int* in_sizes, int n_in,
                              void* d_out, int out_size, void* d_ws, size_t ws_size,
                              hipStream_t stream) {
  const float* x    = (const float*)d_in[0];
  const float* xhat = (const float*)d_in[1];
  const int*   codes= (const int*)d_in[2];
  const float* cb   = (const float*)d_in[3];
  const float* Win  = (const float*)d_in[4];
  const float* bin  = (const float*)d_in[5];
  const float* Wcat = (const float*)d_in[6];
  const float* bcat = (const float*)d_in[7];
  const float* W1   = (const float*)d_in[8];
  const float* b1   = (const float*)d_in[9];
  const float* W2   = (const float*)d_in[10];
  const float* b2   = (const float*)d_in[11];
  const float* Wout = (const float*)d_in[12];
  const float* bout = (const float*)d_in[13];
  float* out = (float*)d_out;

  float* h0    = (float*)d_ws;                 // 65536 floats
  float* u     = h0 + K_ * H_;                 // 65536
  float* v     = u + K_ * H_;                  // 262144
  float* dists = v + B_ * F_ * H_;             // 262144
  int*   idxp  = (int*)(dists + B_ * F_ * K_); // 128

  k_h0<<<K_, 256, 0, stream>>>(cb, Win, bin, h0);
  k_uv<<<K_ + B_ * F_, 256, 0, stream>>>(h0, Wcat, bcat, xhat, u, v);
  k_main<<<B_ * F_ * (K_ / RT), 256, 0, stream>>>(u, v, W1, b1, W2, b2, Wout, bout,
                                                  cb, xhat, x, dists);
  k_argmin<<<B_, 256, 0, stream>>>(dists, idxp);
  k_finalize<<<B_, 256, 0, stream>>>(u, v, W1, b1, W2, b2, Wout, bout, cb, xhat,
                                     codes, idxp, out);
}

// Round 3
// 2327.169 us; speedup vs baseline: 1.9930x; 1.9930x over previous
//
#include <hip/hip_runtime.h>
#include <hip/hip_bf16.h>

// Shapes (fixed): B=128, F=8, K=256, D=256, H=256, HFF=512, L=2, M_PREV=2
#define B_   128
#define F_   8
#define K_   256
#define D_   256
#define H_   256
#define HFF_ 512
#define RT   32   // k-rows per block in main kernel

typedef short short8 __attribute__((ext_vector_type(8)));    // bf16x8 MFMA frag
typedef float floatx4 __attribute__((ext_vector_type(4)));   // MFMA acc

#define MFMA(a,b,c) __builtin_amdgcn_mfma_f32_16x16x32_bf16(a,b,c,0,0,0)

__device__ inline short bf16_rne(float x) {
  union { float f; unsigned u; } v; v.f = x;
  unsigned r = v.u + 0x7fff + ((v.u >> 16) & 1);
  return (short)(r >> 16);
}
__device__ inline float bf16_to_f(short s) {
  union { float f; unsigned u; } v; v.u = ((unsigned)(unsigned short)s) << 16;
  return v.f;
}

// ---------------------------------------------------------------------------
__global__ void k_h0(const float* __restrict__ cb, const float* __restrict__ Win,
                     const float* __restrict__ bin, float* __restrict__ h0) {
  __shared__ float row[D_];
  const int k = blockIdx.x, j = threadIdx.x;
  row[j] = cb[k * D_ + j];
  __syncthreads();
  float acc = bin[j];
  #pragma unroll 4
  for (int i = 0; i < D_; ++i) acc = fmaf(row[i], Win[i * H_ + j], acc);
  h0[k * H_ + j] = acc;
}

__global__ void k_uv(const float* __restrict__ h0, const float* __restrict__ Wcat,
                     const float* __restrict__ bcat, const float* __restrict__ xhat,
                     float* __restrict__ u, float* __restrict__ v) {
  __shared__ float row[D_];
  const int blk = blockIdx.x, j = threadIdx.x;
  if (blk < K_) {
    row[j] = h0[blk * H_ + j];
    __syncthreads();
    float acc = 0.f;
    #pragma unroll 4
    for (int i = 0; i < H_; ++i) acc = fmaf(row[i], Wcat[i * H_ + j], acc);
    u[blk * H_ + j] = acc;
  } else {
    const int bf = blk - K_;
    row[j] = xhat[bf * D_ + j];
    __syncthreads();
    float acc = bcat[j];
    #pragma unroll 4
    for (int i = 0; i < D_; ++i) acc = fmaf(row[i], Wcat[(H_ + i) * H_ + j], acc);
    v[bf * H_ + j] = acc;
  }
}

// ---------------------------------------------------------------------------
// Pre-shuffle a weight matrix [K x N] into MFMA B-fragment order, bf16 hi/lo.
// dst element e = ((kstep*NT + ntile)*64 + lane)*8 + jj
//   value = src[(kstep*32 + (lane>>4)*8 + jj) * N + ntile*16 + (lane&15)]
__global__ void k_wfrag(const float* __restrict__ src, short* __restrict__ dhi,
                        short* __restrict__ dlo, int N, int NT) {
  const int e = blockIdx.x * 256 + threadIdx.x;
  const int jj = e & 7, lane = (e >> 3) & 63, r = e >> 9;
  const int ntile = r % NT, kstep = r / NT;
  const int row = kstep * 32 + (lane >> 4) * 8 + jj;
  const int colc = ntile * 16 + (lane & 15);
  const float val = src[row * N + colc];
  const short hi = bf16_rne(val);
  dhi[e] = hi;
  dlo[e] = bf16_rne(val - bf16_to_f(hi));
}

// ---------------------------------------------------------------------------
// MFMA main kernel: block = one (b,f) x 32 k-candidates. 256 thr = 4 waves.
// bf16 hi/lo 3-term split (hi*hi + hi*lo + lo*hi) ~ fp32-accurate dists.
__global__ __launch_bounds__(256, 2) void k_main(
    const float* __restrict__ u, const float* __restrict__ v,
    const short* __restrict__ w1h, const short* __restrict__ w1l,
    const float* __restrict__ b1,
    const short* __restrict__ w2h, const short* __restrict__ w2l,
    const float* __restrict__ b2,
    const short* __restrict__ wouth, const short* __restrict__ woutl,
    const float* __restrict__ bout,
    const float* __restrict__ cb, const float* __restrict__ xhat,
    const float* __restrict__ x, float* __restrict__ dists) {
  // row strides 264/136 shorts: 132/68 dwords == 4 mod 32 -> even bank spread
  __shared__ short hA_hi[32][264];
  __shared__ short hA_lo[32][264];
  __shared__ short hmA_hi[32][136];
  __shared__ short hmA_lo[32][136];
  __shared__ float x_s[D_], xh_s[D_];
  __shared__ float dist_s[4][32];

  const int t = threadIdx.x;
  const int blk = blockIdx.x;
  const int bf = blk >> 3, k0 = (blk & 7) << 5;
  const int b = bf >> 3, f = bf & 7;
  const int wave = t >> 6, lane = t & 63;
  const int col = lane & 15, quad = lane >> 4;

  x_s[t]  = x[b * D_ + t];
  xh_s[t] = xhat[bf * D_ + t];

  // stage h = u + v, split into bf16 hi/lo
  {
    const int r = t >> 3, c0 = (t & 7) * 32;
    const float* up = u + (k0 + r) * H_ + c0;
    const float* vp = v + bf * H_ + c0;
    #pragma unroll
    for (int j = 0; j < 32; j += 4) {
      float4 uu = *(const float4*)(up + j);
      float4 vv = *(const float4*)(vp + j);
      float hv[4] = {uu.x + vv.x, uu.y + vv.y, uu.z + vv.z, uu.w + vv.w};
      #pragma unroll
      for (int q = 0; q < 4; ++q) {
        short hi = bf16_rne(hv[q]);
        hA_hi[r][c0 + j + q] = hi;
        hA_lo[r][c0 + j + q] = bf16_rne(hv[q] - bf16_to_f(hi));
      }
    }
  }
  __syncthreads();

  const floatx4 zero4 = {0.f, 0.f, 0.f, 0.f};

  for (int l = 0; l < 2; ++l) {
    const short* w1h_l = w1h + l * (H_ * HFF_);
    const short* w1l_l = w1l + l * (H_ * HFF_);
    const short* w2h_l = w2h + l * (HFF_ * H_);
    const short* w2l_l = w2l + l * (HFF_ * H_);
    const float* b1l = b1 + l * HFF_;
    const float* b2l = b2 + l * H_;

    floatx4 acc2[2][4];
    #pragma unroll
    for (int mt = 0; mt < 2; ++mt)
      #pragma unroll
      for (int nt = 0; nt < 4; ++nt) acc2[mt][nt] = zero4;

    for (int ch = 0; ch < 4; ++ch) {
      // ---- GEMM1: hm_chunk = relu(h @ W1[:, ch*128:+128] + b1) ----
      floatx4 acc1[2][2];
      #pragma unroll
      for (int mt = 0; mt < 2; ++mt)
        #pragma unroll
        for (int nt = 0; nt < 2; ++nt) acc1[mt][nt] = zero4;

      #pragma unroll
      for (int ks = 0; ks < 8; ++ks) {
        short8 ah0 = *(const short8*)&hA_hi[col][ks * 32 + quad * 8];
        short8 al0 = *(const short8*)&hA_lo[col][ks * 32 + quad * 8];
        short8 ah1 = *(const short8*)&hA_hi[16 + col][ks * 32 + quad * 8];
        short8 al1 = *(const short8*)&hA_lo[16 + col][ks * 32 + quad * 8];
        #pragma unroll
        for (int nt = 0; nt < 2; ++nt) {
          const int ntile = ch * 8 + wave * 2 + nt;
          const long off = ((long)(ks * 32 + ntile) * 64 + lane) * 8;
          short8 bh = *(const short8*)(w1h_l + off);
          short8 bl = *(const short8*)(w1l_l + off);
          acc1[0][nt] = MFMA(ah0, bh, acc1[0][nt]);
          acc1[0][nt] = MFMA(ah0, bl, acc1[0][nt]);
          acc1[0][nt] = MFMA(al0, bh, acc1[0][nt]);
          acc1[1][nt] = MFMA(ah1, bh, acc1[1][nt]);
          acc1[1][nt] = MFMA(ah1, bl, acc1[1][nt]);
          acc1[1][nt] = MFMA(al1, bh, acc1[1][nt]);
        }
      }
      // bias + relu, split, store to hmA (C layout: row=quad*4+p, col n)
      #pragma unroll
      for (int nt = 0; nt < 2; ++nt) {
        const int nloc = wave * 32 + nt * 16 + col;
        const float bb = b1l[ch * 128 + nloc];
        #pragma unroll
        for (int mt = 0; mt < 2; ++mt)
          #pragma unroll
          for (int p = 0; p < 4; ++p) {
            const int m = mt * 16 + quad * 4 + p;
            float hm = fmaxf(acc1[mt][nt][p] + bb, 0.f);
            short hi = bf16_rne(hm);
            hmA_hi[m][nloc] = hi;
            hmA_lo[m][nloc] = bf16_rne(hm - bf16_to_f(hi));
          }
      }
      __syncthreads();

      // ---- GEMM2: acc2 += hm_chunk @ W2[ch*128:+128, :] ----
      #pragma unroll
      for (int ks = 0; ks < 4; ++ks) {
        short8 ah0 = *(const short8*)&hmA_hi[col][ks * 32 + quad * 8];
        short8 al0 = *(const short8*)&hmA_lo[col][ks * 32 + quad * 8];
        short8 ah1 = *(const short8*)&hmA_hi[16 + col][ks * 32 + quad * 8];
        short8 al1 = *(const short8*)&hmA_lo[16 + col][ks * 32 + quad * 8];
        const int ksg = ch * 4 + ks;
        #pragma unroll
        for (int nt = 0; nt < 4; ++nt) {
          const int ntile = wave * 4 + nt;
          const long off = ((long)(ksg * 16 + ntile) * 64 + lane) * 8;
          short8 bh = *(const short8*)(w2h_l + off);
          short8 bl = *(const short8*)(w2l_l + off);
          acc2[0][nt] = MFMA(ah0, bh, acc2[0][nt]);
          acc2[0][nt] = MFMA(ah0, bl, acc2[0][nt]);
          acc2[0][nt] = MFMA(al0, bh, acc2[0][nt]);
          acc2[1][nt] = MFMA(ah1, bh, acc2[1][nt]);
          acc2[1][nt] = MFMA(ah1, bl, acc2[1][nt]);
          acc2[1][nt] = MFMA(al1, bh, acc2[1][nt]);
        }
      }
      __syncthreads();
    }

    // ---- residual: h += acc2 + b2 (each (m,n) touched by exactly one lane) --
    #pragma unroll
    for (int nt = 0; nt < 4; ++nt) {
      const int n = wave * 64 + nt * 16 + col;
      const float bb = b2l[n];
      #pragma unroll
      for (int mt = 0; mt < 2; ++mt)
        #pragma unroll
        for (int p = 0; p < 4; ++p) {
          const int m = mt * 16 + quad * 4 + p;
          float hold = bf16_to_f(hA_hi[m][n]) + bf16_to_f(hA_lo[m][n]);
          float hnew = hold + acc2[mt][nt][p] + bb;
          short hi = bf16_rne(hnew);
          hA_hi[m][n] = hi;
          hA_lo[m][n] = bf16_rne(hnew - bf16_to_f(hi));
        }
    }
    __syncthreads();
  }

  // ---- GEMM3: cw = h @ W_out (+ bout + cb + xhat), then distance ----
  floatx4 acc3[2][4];
  #pragma unroll
  for (int mt = 0; mt < 2; ++mt)
    #pragma unroll
    for (int nt = 0; nt < 4; ++nt) acc3[mt][nt] = zero4;

  #pragma unroll
  for (int ks = 0; ks < 8; ++ks) {
    short8 ah0 = *(const short8*)&hA_hi[col][ks * 32 + quad * 8];
    short8 al0 = *(const short8*)&hA_lo[col][ks * 32 + quad * 8];
    short8 ah1 = *(const short8*)&hA_hi[16 + col][ks * 32 + quad * 8];
    short8 al1 = *(const short8*)&hA_lo[16 + col][ks * 32 + quad * 8];
    #pragma unroll
    for (int nt = 0; nt < 4; ++nt) {
      const int ntile = wave * 4 + nt;
      const long off = ((long)(ks * 16 + ntile) * 64 + lane) * 8;
      short8 bh = *(const short8*)(wouth + off);
      short8 bl = *(const short8*)(woutl + off);
      acc3[0][nt] = MFMA(ah0, bh, acc3[0][nt]);
      acc3[0][nt] = MFMA(ah0, bl, acc3[0][nt]);
      acc3[0][nt] = MFMA(al0, bh, acc3[0][nt]);
      acc3[1][nt] = MFMA(ah1, bh, acc3[1][nt]);
      acc3[1][nt] = MFMA(ah1, bl, acc3[1][nt]);
      acc3[1][nt] = MFMA(al1, bh, acc3[1][nt]);
    }
  }

  float pd[8];
  #pragma unroll
  for (int mt = 0; mt < 2; ++mt)
    #pragma unroll
    for (int p = 0; p < 4; ++p) {
      const int m = mt * 16 + quad * 4 + p;
      const int k = k0 + m;
      float s = 0.f;
      #pragma unroll
      for (int nt = 0; nt < 4; ++nt) {
        const int n = wave * 64 + nt * 16 + col;
        float y = acc3[mt][nt][p] + bout[n] + xh_s[n];
        float cw = y + cb[k * D_ + n];
        s += cw * (cw - 2.f * x_s[n]);   // -||x||^2 const: argmin-invariant
      }
      pd[mt * 4 + p] = s;
    }
  #pragma unroll
  for (int msk = 1; msk < 16; msk <<= 1)
    #pragma unroll
    for (int q = 0; q < 8; ++q)
      pd[q] += __shfl_xor(pd[q], msk, 64);

  if (col == 0) {
    #pragma unroll
    for (int mt = 0; mt < 2; ++mt)
      #pragma unroll
      for (int p = 0; p < 4; ++p)
        dist_s[wave][mt * 16 + quad * 4 + p] = pd[mt * 4 + p];
  }
  __syncthreads();
  if (t < 32) {
    float d = dist_s[0][t] + dist_s[1][t] + dist_s[2][t] + dist_s[3][t];
    dists[b * (F_ * K_) + f * K_ + k0 + t] = d;
  }
}

// ---------------------------------------------------------------------------
// Top-8 candidates per b from approx dists (iterative selection).
__global__ void k_top8(const float* __restrict__ dists, int* __restrict__ topi) {
  __shared__ float ds[F_ * K_];
  __shared__ float bv[256];
  __shared__ int bi_s[256];
  const int b = blockIdx.x, t = threadIdx.x;
  for (int j = t; j < F_ * K_; j += 256) ds[j] = dists[b * (F_ * K_) + j];
  __syncthreads();
  for (int pass = 0; pass < 8; ++pass) {
    float best = 3.4e38f; int bi = 0;
    for (int j = t; j < F_ * K_; j += 256) {
      const float dv = ds[j];
      if (dv < best) { best = dv; bi = j; }
    }
    bv[t] = best; bi_s[t] = bi;
    __syncthreads();
    for (int s = 128; s > 0; s >>= 1) {
      if (t < s) {
        const float ov = bv[t + s]; const int oi = bi_s[t + s];
        if (ov < bv[t] || (ov == bv[t] && oi < bi_s[t])) { bv[t] = ov; bi_s[t] = oi; }
      }
      __syncthreads();
    }
    if (t == 0) { topi[b * 8 + pass] = bi_s[0]; ds[bi_s[0]] = 3.4e38f; }
    __syncthreads();
  }
}

// ---------------------------------------------------------------------------
// Exact fp32 rescore of one candidate row per block (same math that passed R2).
__global__ void k_rescore(const float* __restrict__ u, const float* __restrict__ v,
                          const float* __restrict__ W1, const float* __restrict__ b1,
                          const float* __restrict__ W2, const float* __restrict__ b2,
                          const float* __restrict__ Wout, const float* __restrict__ bout,
                          const float* __restrict__ cb, const float* __restrict__ xhat,
                          const float* __restrict__ x, const int* __restrict__ topi,
                          float* __restrict__ resc) {
  __shared__ float hs[H_];
  __shared__ float hms[HFF_];
  __shared__ float red[256];
  const int bc = blockIdx.x, t = threadIdx.x;
  const int b = bc >> 3;
  const int idx = topi[bc];
  const int f = idx >> 8, k = idx & 255;
  const int bf = b * F_ + f;

  hs[t] = u[k * H_ + t] + v[bf * H_ + t];
  __syncthreads();
  for (int l = 0; l < 2; ++l) {
    const float* W1l = W1 + l * (H_ * HFF_);
    const float* W2l = W2 + l * (HFF_ * H_);
    float a0 = b1[l * HFF_ + t], a1 = b1[l * HFF_ + 256 + t];
    for (int i = 0; i < H_; ++i) {
      const float hv = hs[i];
      a0 = fmaf(hv, W1l[i * HFF_ + t], a0);
      a1 = fmaf(hv, W1l[i * HFF_ + 256 + t], a1);
    }
    hms[t] = fmaxf(a0, 0.f);
    hms[t + 256] = fmaxf(a1, 0.f);
    __syncthreads();
    float hn = hs[t] + b2[l * H_ + t];
    for (int jj = 0; jj < HFF_; ++jj)
      hn = fmaf(hms[jj], W2l[jj * H_ + t], hn);
    __syncthreads();
    hs[t] = hn;
    __syncthreads();
  }
  float cw = bout[t] + cb[k * D_ + t] + xhat[bf * D_ + t];
  for (int i = 0; i < H_; ++i) cw = fmaf(hs[i], Wout[i * D_ + t], cw);
  red[t] = cw * (cw - 2.f * x[b * D_ + t]);
  __syncthreads();
  for (int s = 128; s > 0; s >>= 1) {
    if (t < s) red[t] += red[t + s];
    __syncthreads();
  }
  if (t == 0) resc[bc] = red[0];
}

// ---------------------------------------------------------------------------
// Pick exact argmin among 8 rescored candidates; recompute winner; write out.
__global__ void k_final(const float* __restrict__ u, const float* __restrict__ v,
                        const float* __restrict__ W1, const float* __restrict__ b1,
                        const float* __restrict__ W2, const float* __restrict__ b2,
                        const float* __restrict__ Wout, const float* __restrict__ bout,
                        const float* __restrict__ cb, const float* __restrict__ xhat,
                        const int* __restrict__ codes, const int* __restrict__ topi,
                        const float* __restrict__ resc, float* __restrict__ out) {
  __shared__ float hs[H_];
  __shared__ float hms[HFF_];
  __shared__ int idx_sh;
  const int b = blockIdx.x, t = threadIdx.x;
  if (t == 0) {
    float bd = 3.4e38f; int bidx = 1 << 30;
    for (int c = 0; c < 8; ++c) {
      const float d = resc[b * 8 + c];
      const int ix = topi[b * 8 + c];
      if (d < bd || (d == bd && ix < bidx)) { bd = d; bidx = ix; }
    }
    idx_sh = bidx;
  }
  __syncthreads();
  const int idx = idx_sh;
  const int f = idx >> 8, k = idx & 255;
  const int bf = b * F_ + f;

  hs[t] = u[k * H_ + t] + v[bf * H_ + t];
  __syncthreads();
  for (int l = 0; l < 2; ++l) {
    const float* W1l = W1 + l * (H_ * HFF_);
    const float* W2l = W2 + l * (HFF_ * H_);
    float a0 = b1[l * HFF_ + t], a1 = b1[l * HFF_ + 256 + t];
    for (int i = 0; i < H_; ++i) {
      const float hv = hs[i];
      a0 = fmaf(hv, W1l[i * HFF_ + t], a0);
      a1 = fmaf(hv, W1l[i * HFF_ + 256 + t], a1);
    }
    hms[t] = fmaxf(a0, 0.f);
    hms[t + 256] = fmaxf(a1, 0.f);
    __syncthreads();
    float hn = hs[t] + b2[l * H_ + t];
    for (int jj = 0; jj < HFF_; ++jj)
      hn = fmaf(hms[jj], W2l[jj * H_ + t], hn);
    __syncthreads();
    hs[t] = hn;
    __syncthreads();
  }
  float cw = bout[t] + cb[k * D_ + t] + xhat[bf * D_ + t];
  for (int i = 0; i < H_; ++i) cw = fmaf(hs[i], Wout[i * D_ + t], cw);

  out[b * D_ + t] = cw;
  if (t < 2)
    out[B_ * D_ + t * B_ + b] = (float)codes[t * B_ + b];
  else if (t == 2)
    out[B_ * D_ + 2 * B_ + b] = (float)idx;
}

// ---------------------------------------------------------------------------
extern "C" void kernel_launch(void* const* d_in, const int* in_sizes, int n_in,
                              void* d_out, int out_size, void* d_ws, size_t ws_size,
                              hipStream_t stream) {
  const float* x    = (const float*)d_in[0];
  const float* xhat = (const float*)d_in[1];
  const int*   codes= (const int*)d_in[2];
  const float* cb   = (const float*)d_in[3];
  const float* Win  = (const float*)d_in[4];
  const float* bin  = (const float*)d_in[5];
  const float* Wcat = (const float*)d_in[6];
  const float* bcat = (const float*)d_in[7];
  const float* W1   = (const float*)d_in[8];
  const float* b1   = (const float*)d_in[9];
  const float* W2   = (const float*)d_in[10];
  const float* b2   = (const float*)d_in[11];
  const float* Wout = (const float*)d_in[12];
  const float* bout = (const float*)d_in[13];
  float* out = (float*)d_out;

  float* h0    = (float*)d_ws;                  // 65536 f
  float* u     = h0 + K_ * H_;                  // 65536 f
  float* v     = u + K_ * H_;                   // 262144 f
  float* dists = v + B_ * F_ * H_;              // 262144 f
  float* resc  = dists + B_ * F_ * K_;          // 1024 f
  int*   topi  = (int*)(resc + 1024);           // 1024 i
  int*   pad   = topi + 1024;                   // 128 pad (keeps 16B align)
  short* w1h   = (short*)(pad + 128);           // 262144 sh
  short* w1l   = w1h + 2 * H_ * HFF_;
  short* w2h   = w1l + 2 * H_ * HFF_;
  short* w2l   = w2h + 2 * HFF_ * H_;
  short* wouth = w2l + 2 * HFF_ * H_;
  short* woutl = wouth + H_ * D_;

  k_h0<<<K_, 256, 0, stream>>>(cb, Win, bin, h0);
  k_uv<<<K_ + B_ * F_, 256, 0, stream>>>(h0, Wcat, bcat, xhat, u, v);
  // fragment-order bf16 hi/lo weights
  k_wfrag<<<512, 256, 0, stream>>>(W1, w1h, w1l, HFF_, 32);
  k_wfrag<<<512, 256, 0, stream>>>(W1 + H_ * HFF_, w1h + H_ * HFF_, w1l + H_ * HFF_, HFF_, 32);
  k_wfrag<<<512, 256, 0, stream>>>(W2, w2h, w2l, H_, 16);
  k_wfrag<<<512, 256, 0, stream>>>(W2 + HFF_ * H_, w2h + HFF_ * H_, w2l + HFF_ * H_, H_, 16);
  k_wfrag<<<256, 256, 0, stream>>>(Wout, wouth, woutl, D_, 16);

  k_main<<<B_ * F_ * (K_ / RT), 256, 0, stream>>>(u, v, w1h, w1l, b1, w2h, w2l, b2,
                                                  wouth, woutl, bout, cb, xhat, x, dists);
  k_top8<<<B_, 256, 0, stream>>>(dists, topi);
  k_rescore<<<B_ * 8, 256, 0, stream>>>(u, v, W1, b1, W2, b2, Wout, bout, cb, xhat,
                                        x, topi, resc);
  k_final<<<B_, 256, 0, stream>>>(u, v, W1, b1, W2, b2, Wout, bout, cb, xhat,
                                  codes, topi, resc, out);
}

// Round 4
// 1074.063 us; speedup vs baseline: 4.3183x; 2.1667x over previous
//
#include <hip/hip_runtime.h>
#include <hip/hip_bf16.h>

// Shapes (fixed): B=128, F=8, K=256, D=256, H=256, HFF=512, L=2, M_PREV=2
#define B_   128
#define F_   8
#define K_   256
#define D_   256
#define H_   256
#define HFF_ 512
#define RT   32   // k-rows per block in main kernel

typedef short short8 __attribute__((ext_vector_type(8)));    // bf16x8 MFMA frag
typedef float floatx4 __attribute__((ext_vector_type(4)));   // MFMA acc

#define MFMA(a,b,c) __builtin_amdgcn_mfma_f32_16x16x32_bf16(a,b,c,0,0,0)

__device__ inline short bf16_rne(float x) {
  union { float f; unsigned u; } v; v.f = x;
  unsigned r = v.u + 0x7fff + ((v.u >> 16) & 1);
  return (short)(r >> 16);
}
__device__ inline float bf16_to_f(short s) {
  union { float f; unsigned u; } v; v.u = ((unsigned)(unsigned short)s) << 16;
  return v.f;
}

// ---------------------------------------------------------------------------
__global__ void k_h0(const float* __restrict__ cb, const float* __restrict__ Win,
                     const float* __restrict__ bin, float* __restrict__ h0) {
  __shared__ float row[D_];
  const int k = blockIdx.x, j = threadIdx.x;
  row[j] = cb[k * D_ + j];
  __syncthreads();
  float acc = bin[j];
  #pragma unroll 4
  for (int i = 0; i < D_; ++i) acc = fmaf(row[i], Win[i * H_ + j], acc);
  h0[k * H_ + j] = acc;
}

__global__ void k_uv(const float* __restrict__ h0, const float* __restrict__ Wcat,
                     const float* __restrict__ bcat, const float* __restrict__ xhat,
                     float* __restrict__ u, float* __restrict__ v) {
  __shared__ float row[D_];
  const int blk = blockIdx.x, j = threadIdx.x;
  if (blk < K_) {
    row[j] = h0[blk * H_ + j];
    __syncthreads();
    float acc = 0.f;
    #pragma unroll 4
    for (int i = 0; i < H_; ++i) acc = fmaf(row[i], Wcat[i * H_ + j], acc);
    u[blk * H_ + j] = acc;
  } else {
    const int bf = blk - K_;
    row[j] = xhat[bf * D_ + j];
    __syncthreads();
    float acc = bcat[j];
    #pragma unroll 4
    for (int i = 0; i < D_; ++i) acc = fmaf(row[i], Wcat[(H_ + i) * H_ + j], acc);
    v[bf * H_ + j] = acc;
  }
}

// ---------------------------------------------------------------------------
// Pre-shuffle a weight matrix [K x N] into MFMA B-fragment order, bf16 hi/lo.
__global__ void k_wfrag(const float* __restrict__ src, short* __restrict__ dhi,
                        short* __restrict__ dlo, int N, int NT) {
  const int e = blockIdx.x * 256 + threadIdx.x;
  const int jj = e & 7, lane = (e >> 3) & 63, r = e >> 9;
  const int ntile = r % NT, kstep = r / NT;
  const int row = kstep * 32 + (lane >> 4) * 8 + jj;
  const int colc = ntile * 16 + (lane & 15);
  const float val = src[row * N + colc];
  const short hi = bf16_rne(val);
  dhi[e] = hi;
  dlo[e] = bf16_rne(val - bf16_to_f(hi));
}

// ---------------------------------------------------------------------------
// MFMA main kernel: block = one (b,f) x 32 k-candidates. 256 thr = 4 waves.
// bf16 hi/lo 3-term split (hi*hi + hi*lo + lo*hi) ~ fp32-accurate dists.
// R4: anti-spill restructure — unroll 2 on ks loops, int offsets, hoisted
// per-wave base pointers. (R3 spilled ~820 MB each way to scratch.)
__global__ __launch_bounds__(256, 2) void k_main(
    const float* __restrict__ u, const float* __restrict__ v,
    const short* __restrict__ w1h, const short* __restrict__ w1l,
    const float* __restrict__ b1,
    const short* __restrict__ w2h, const short* __restrict__ w2l,
    const float* __restrict__ b2,
    const short* __restrict__ wouth, const short* __restrict__ woutl,
    const float* __restrict__ bout,
    const float* __restrict__ cb, const float* __restrict__ xhat,
    const float* __restrict__ x, float* __restrict__ dists) {
  __shared__ short hA_hi[32][264];
  __shared__ short hA_lo[32][264];
  __shared__ short hmA_hi[32][136];
  __shared__ short hmA_lo[32][136];
  __shared__ float x_s[D_], xh_s[D_];
  __shared__ float dist_s[4][32];

  const int t = threadIdx.x;
  const int blk = blockIdx.x;
  const int bf = blk >> 3, k0 = (blk & 7) << 5;
  const int b = bf >> 3, f = bf & 7;
  const int wave = t >> 6, lane = t & 63;
  const int col = lane & 15, quad = lane >> 4;
  const int lane8 = lane * 8;

  x_s[t]  = x[b * D_ + t];
  xh_s[t] = xhat[bf * D_ + t];

  // stage h = u + v, split into bf16 hi/lo
  {
    const int r = t >> 3, c0 = (t & 7) * 32;
    const float* up = u + (k0 + r) * H_ + c0;
    const float* vp = v + bf * H_ + c0;
    #pragma unroll
    for (int j = 0; j < 32; j += 4) {
      float4 uu = *(const float4*)(up + j);
      float4 vv = *(const float4*)(vp + j);
      float hv[4] = {uu.x + vv.x, uu.y + vv.y, uu.z + vv.z, uu.w + vv.w};
      #pragma unroll
      for (int q = 0; q < 4; ++q) {
        short hi = bf16_rne(hv[q]);
        hA_hi[r][c0 + j + q] = hi;
        hA_lo[r][c0 + j + q] = bf16_rne(hv[q] - bf16_to_f(hi));
      }
    }
  }
  __syncthreads();

  const floatx4 zero4 = {0.f, 0.f, 0.f, 0.f};

  #pragma unroll 1
  for (int l = 0; l < 2; ++l) {
    const short* w1h_l = w1h + l * (H_ * HFF_);
    const short* w1l_l = w1l + l * (H_ * HFF_);
    const short* w2h_l = w2h + l * (HFF_ * H_);
    const short* w2l_l = w2l + l * (HFF_ * H_);
    const float* b1l = b1 + l * HFF_;
    const float* b2l = b2 + l * H_;

    floatx4 acc2[2][4];
    #pragma unroll
    for (int mt = 0; mt < 2; ++mt)
      #pragma unroll
      for (int nt = 0; nt < 4; ++nt) acc2[mt][nt] = zero4;

    #pragma unroll 1
    for (int ch = 0; ch < 4; ++ch) {
      // ---- GEMM1: hm_chunk = relu(h @ W1[:, ch*128:+128] + b1) ----
      floatx4 acc1[2][2];
      #pragma unroll
      for (int mt = 0; mt < 2; ++mt)
        #pragma unroll
        for (int nt = 0; nt < 2; ++nt) acc1[mt][nt] = zero4;

      // base frag index for (ks=0, ntile=ch*8+wave*2): ((0+ntile)*64+lane)*8
      const short* w1h_b = w1h_l + (ch * 8 + wave * 2) * 512 + lane8;
      const short* w1l_b = w1l_l + (ch * 8 + wave * 2) * 512 + lane8;

      #pragma unroll 2
      for (int ks = 0; ks < 8; ++ks) {
        short8 ah0 = *(const short8*)&hA_hi[col][ks * 32 + quad * 8];
        short8 al0 = *(const short8*)&hA_lo[col][ks * 32 + quad * 8];
        short8 ah1 = *(const short8*)&hA_hi[16 + col][ks * 32 + quad * 8];
        short8 al1 = *(const short8*)&hA_lo[16 + col][ks * 32 + quad * 8];
        const int ko = ks * 32 * 512;   // ks*32 frags * 512 shorts
        #pragma unroll
        for (int nt = 0; nt < 2; ++nt) {
          const int off = ko + nt * 512;
          short8 bh = *(const short8*)(w1h_b + off);
          short8 bl = *(const short8*)(w1l_b + off);
          acc1[0][nt] = MFMA(ah0, bh, acc1[0][nt]);
          acc1[0][nt] = MFMA(ah0, bl, acc1[0][nt]);
          acc1[0][nt] = MFMA(al0, bh, acc1[0][nt]);
          acc1[1][nt] = MFMA(ah1, bh, acc1[1][nt]);
          acc1[1][nt] = MFMA(ah1, bl, acc1[1][nt]);
          acc1[1][nt] = MFMA(al1, bh, acc1[1][nt]);
        }
      }
      // bias + relu, split, store to hmA (C layout: row=quad*4+p, col n)
      #pragma unroll
      for (int nt = 0; nt < 2; ++nt) {
        const int nloc = wave * 32 + nt * 16 + col;
        const float bb = b1l[ch * 128 + nloc];
        #pragma unroll
        for (int mt = 0; mt < 2; ++mt)
          #pragma unroll
          for (int p = 0; p < 4; ++p) {
            const int m = mt * 16 + quad * 4 + p;
            float hm = fmaxf(acc1[mt][nt][p] + bb, 0.f);
            short hi = bf16_rne(hm);
            hmA_hi[m][nloc] = hi;
            hmA_lo[m][nloc] = bf16_rne(hm - bf16_to_f(hi));
          }
      }
      __syncthreads();

      // ---- GEMM2: acc2 += hm_chunk @ W2[ch*128:+128, :] ----
      const short* w2h_b = w2h_l + (ch * 4 * 16 + wave * 4) * 512 + lane8;
      const short* w2l_b = w2l_l + (ch * 4 * 16 + wave * 4) * 512 + lane8;
      #pragma unroll 2
      for (int ks = 0; ks < 4; ++ks) {
        short8 ah0 = *(const short8*)&hmA_hi[col][ks * 32 + quad * 8];
        short8 al0 = *(const short8*)&hmA_lo[col][ks * 32 + quad * 8];
        short8 ah1 = *(const short8*)&hmA_hi[16 + col][ks * 32 + quad * 8];
        short8 al1 = *(const short8*)&hmA_lo[16 + col][ks * 32 + quad * 8];
        const int ko = ks * 16 * 512;
        #pragma unroll
        for (int nt = 0; nt < 4; ++nt) {
          const int off = ko + nt * 512;
          short8 bh = *(const short8*)(w2h_b + off);
          short8 bl = *(const short8*)(w2l_b + off);
          acc2[0][nt] = MFMA(ah0, bh, acc2[0][nt]);
          acc2[0][nt] = MFMA(ah0, bl, acc2[0][nt]);
          acc2[0][nt] = MFMA(al0, bh, acc2[0][nt]);
          acc2[1][nt] = MFMA(ah1, bh, acc2[1][nt]);
          acc2[1][nt] = MFMA(ah1, bl, acc2[1][nt]);
          acc2[1][nt] = MFMA(al1, bh, acc2[1][nt]);
        }
      }
      __syncthreads();
    }

    // ---- residual: h += acc2 + b2 (each (m,n) touched by exactly one lane) --
    #pragma unroll
    for (int nt = 0; nt < 4; ++nt) {
      const int n = wave * 64 + nt * 16 + col;
      const float bb = b2l[n];
      #pragma unroll
      for (int mt = 0; mt < 2; ++mt)
        #pragma unroll
        for (int p = 0; p < 4; ++p) {
          const int m = mt * 16 + quad * 4 + p;
          float hold = bf16_to_f(hA_hi[m][n]) + bf16_to_f(hA_lo[m][n]);
          float hnew = hold + acc2[mt][nt][p] + bb;
          short hi = bf16_rne(hnew);
          hA_hi[m][n] = hi;
          hA_lo[m][n] = bf16_rne(hnew - bf16_to_f(hi));
        }
    }
    __syncthreads();
  }

  // ---- GEMM3: cw = h @ W_out (+ bout + cb + xhat), then distance ----
  floatx4 acc3[2][4];
  #pragma unroll
  for (int mt = 0; mt < 2; ++mt)
    #pragma unroll
    for (int nt = 0; nt < 4; ++nt) acc3[mt][nt] = zero4;

  const short* woh_b = wouth + (wave * 4) * 512 + lane8;
  const short* wol_b = woutl + (wave * 4) * 512 + lane8;
  #pragma unroll 2
  for (int ks = 0; ks < 8; ++ks) {
    short8 ah0 = *(const short8*)&hA_hi[col][ks * 32 + quad * 8];
    short8 al0 = *(const short8*)&hA_lo[col][ks * 32 + quad * 8];
    short8 ah1 = *(const short8*)&hA_hi[16 + col][ks * 32 + quad * 8];
    short8 al1 = *(const short8*)&hA_lo[16 + col][ks * 32 + quad * 8];
    const int ko = ks * 16 * 512;
    #pragma unroll
    for (int nt = 0; nt < 4; ++nt) {
      const int off = ko + nt * 512;
      short8 bh = *(const short8*)(woh_b + off);
      short8 bl = *(const short8*)(wol_b + off);
      acc3[0][nt] = MFMA(ah0, bh, acc3[0][nt]);
      acc3[0][nt] = MFMA(ah0, bl, acc3[0][nt]);
      acc3[0][nt] = MFMA(al0, bh, acc3[0][nt]);
      acc3[1][nt] = MFMA(ah1, bh, acc3[1][nt]);
      acc3[1][nt] = MFMA(ah1, bl, acc3[1][nt]);
      acc3[1][nt] = MFMA(al1, bh, acc3[1][nt]);
    }
  }

  float pd[8];
  #pragma unroll
  for (int mt = 0; mt < 2; ++mt)
    #pragma unroll
    for (int p = 0; p < 4; ++p) {
      const int m = mt * 16 + quad * 4 + p;
      const int k = k0 + m;
      float s = 0.f;
      #pragma unroll
      for (int nt = 0; nt < 4; ++nt) {
        const int n = wave * 64 + nt * 16 + col;
        float y = acc3[mt][nt][p] + bout[n] + xh_s[n];
        float cw = y + cb[k * D_ + n];
        s += cw * (cw - 2.f * x_s[n]);   // -||x||^2 const: argmin-invariant
      }
      pd[mt * 4 + p] = s;
    }
  #pragma unroll
  for (int msk = 1; msk < 16; msk <<= 1)
    #pragma unroll
    for (int q = 0; q < 8; ++q)
      pd[q] += __shfl_xor(pd[q], msk, 64);

  if (col == 0) {
    #pragma unroll
    for (int mt = 0; mt < 2; ++mt)
      #pragma unroll
      for (int p = 0; p < 4; ++p)
        dist_s[wave][mt * 16 + quad * 4 + p] = pd[mt * 4 + p];
  }
  __syncthreads();
  if (t < 32) {
    float d = dist_s[0][t] + dist_s[1][t] + dist_s[2][t] + dist_s[3][t];
    dists[b * (F_ * K_) + f * K_ + k0 + t] = d;
  }
}

// ---------------------------------------------------------------------------
// Top-8 candidates per b from approx dists (iterative selection).
__global__ void k_top8(const float* __restrict__ dists, int* __restrict__ topi) {
  __shared__ float ds[F_ * K_];
  __shared__ float bv[256];
  __shared__ int bi_s[256];
  const int b = blockIdx.x, t = threadIdx.x;
  for (int j = t; j < F_ * K_; j += 256) ds[j] = dists[b * (F_ * K_) + j];
  __syncthreads();
  for (int pass = 0; pass < 8; ++pass) {
    float best = 3.4e38f; int bi = 0;
    for (int j = t; j < F_ * K_; j += 256) {
      const float dv = ds[j];
      if (dv < best) { best = dv; bi = j; }
    }
    bv[t] = best; bi_s[t] = bi;
    __syncthreads();
    for (int s = 128; s > 0; s >>= 1) {
      if (t < s) {
        const float ov = bv[t + s]; const int oi = bi_s[t + s];
        if (ov < bv[t] || (ov == bv[t] && oi < bi_s[t])) { bv[t] = ov; bi_s[t] = oi; }
      }
      __syncthreads();
    }
    if (t == 0) { topi[b * 8 + pass] = bi_s[0]; ds[bi_s[0]] = 3.4e38f; }
    __syncthreads();
  }
}

// ---------------------------------------------------------------------------
// Exact fp32 rescore of one candidate row per block (same math as R2 pass).
__global__ void k_rescore(const float* __restrict__ u, const float* __restrict__ v,
                          const float* __restrict__ W1, const float* __restrict__ b1,
                          const float* __restrict__ W2, const float* __restrict__ b2,
                          const float* __restrict__ Wout, const float* __restrict__ bout,
                          const float* __restrict__ cb, const float* __restrict__ xhat,
                          const float* __restrict__ x, const int* __restrict__ topi,
                          float* __restrict__ resc) {
  __shared__ float hs[H_];
  __shared__ float hms[HFF_];
  __shared__ float red[256];
  const int bc = blockIdx.x, t = threadIdx.x;
  const int b = bc >> 3;
  const int idx = topi[bc];
  const int f = idx >> 8, k = idx & 255;
  const int bf = b * F_ + f;

  hs[t] = u[k * H_ + t] + v[bf * H_ + t];
  __syncthreads();
  for (int l = 0; l < 2; ++l) {
    const float* W1l = W1 + l * (H_ * HFF_);
    const float* W2l = W2 + l * (HFF_ * H_);
    float a0 = b1[l * HFF_ + t], a1 = b1[l * HFF_ + 256 + t];
    for (int i = 0; i < H_; ++i) {
      const float hv = hs[i];
      a0 = fmaf(hv, W1l[i * HFF_ + t], a0);
      a1 = fmaf(hv, W1l[i * HFF_ + 256 + t], a1);
    }
    hms[t] = fmaxf(a0, 0.f);
    hms[t + 256] = fmaxf(a1, 0.f);
    __syncthreads();
    float hn = hs[t] + b2[l * H_ + t];
    for (int jj = 0; jj < HFF_; ++jj)
      hn = fmaf(hms[jj], W2l[jj * H_ + t], hn);
    __syncthreads();
    hs[t] = hn;
    __syncthreads();
  }
  float cw = bout[t] + cb[k * D_ + t] + xhat[bf * D_ + t];
  for (int i = 0; i < H_; ++i) cw = fmaf(hs[i], Wout[i * D_ + t], cw);
  red[t] = cw * (cw - 2.f * x[b * D_ + t]);
  __syncthreads();
  for (int s = 128; s > 0; s >>= 1) {
    if (t < s) red[t] += red[t + s];
    __syncthreads();
  }
  if (t == 0) resc[bc] = red[0];
}

// ---------------------------------------------------------------------------
// Pick exact argmin among 8 rescored candidates; recompute winner; write out.
__global__ void k_final(const float* __restrict__ u, const float* __restrict__ v,
                        const float* __restrict__ W1, const float* __restrict__ b1,
                        const float* __restrict__ W2, const float* __restrict__ b2,
                        const float* __restrict__ Wout, const float* __restrict__ bout,
                        const float* __restrict__ cb, const float* __restrict__ xhat,
                        const int* __restrict__ codes, const int* __restrict__ topi,
                        const float* __restrict__ resc, float* __restrict__ out) {
  __shared__ float hs[H_];
  __shared__ float hms[HFF_];
  __shared__ int idx_sh;
  const int b = blockIdx.x, t = threadIdx.x;
  if (t == 0) {
    float bd = 3.4e38f; int bidx = 1 << 30;
    for (int c = 0; c < 8; ++c) {
      const float d = resc[b * 8 + c];
      const int ix = topi[b * 8 + c];
      if (d < bd || (d == bd && ix < bidx)) { bd = d; bidx = ix; }
    }
    idx_sh = bidx;
  }
  __syncthreads();
  const int idx = idx_sh;
  const int f = idx >> 8, k = idx & 255;
  const int bf = b * F_ + f;

  hs[t] = u[k * H_ + t] + v[bf * H_ + t];
  __syncthreads();
  for (int l = 0; l < 2; ++l) {
    const float* W1l = W1 + l * (H_ * HFF_);
    const float* W2l = W2 + l * (HFF_ * H_);
    float a0 = b1[l * HFF_ + t], a1 = b1[l * HFF_ + 256 + t];
    for (int i = 0; i < H_; ++i) {
      const float hv = hs[i];
      a0 = fmaf(hv, W1l[i * HFF_ + t], a0);
      a1 = fmaf(hv, W1l[i * HFF_ + 256 + t], a1);
    }
    hms[t] = fmaxf(a0, 0.f);
    hms[t + 256] = fmaxf(a1, 0.f);
    __syncthreads();
    float hn = hs[t] + b2[l * H_ + t];
    for (int jj = 0; jj < HFF_; ++jj)
      hn = fmaf(hms[jj], W2l[jj * H_ + t], hn);
    __syncthreads();
    hs[t] = hn;
    __syncthreads();
  }
  float cw = bout[t] + cb[k * D_ + t] + xhat[bf * D_ + t];
  for (int i = 0; i < H_; ++i) cw = fmaf(hs[i], Wout[i * D_ + t], cw);

  out[b * D_ + t] = cw;
  if (t < 2)
    out[B_ * D_ + t * B_ + b] = (float)codes[t * B_ + b];
  else if (t == 2)
    out[B_ * D_ + 2 * B_ + b] = (float)idx;
}

// ---------------------------------------------------------------------------
extern "C" void kernel_launch(void* const* d_in, const int* in_sizes, int n_in,
                              void* d_out, int out_size, void* d_ws, size_t ws_size,
                              hipStream_t stream) {
  const float* x    = (const float*)d_in[0];
  const float* xhat = (const float*)d_in[1];
  const int*   codes= (const int*)d_in[2];
  const float* cb   = (const float*)d_in[3];
  const float* Win  = (const float*)d_in[4];
  const float* bin  = (const float*)d_in[5];
  const float* Wcat = (const float*)d_in[6];
  const float* bcat = (const float*)d_in[7];
  const float* W1   = (const float*)d_in[8];
  const float* b1   = (const float*)d_in[9];
  const float* W2   = (const float*)d_in[10];
  const float* b2   = (const float*)d_in[11];
  const float* Wout = (const float*)d_in[12];
  const float* bout = (const float*)d_in[13];
  float* out = (float*)d_out;

  float* h0    = (float*)d_ws;                  // 65536 f
  float* u     = h0 + K_ * H_;                  // 65536 f
  float* v     = u + K_ * H_;                   // 262144 f
  float* dists = v + B_ * F_ * H_;              // 262144 f
  float* resc  = dists + B_ * F_ * K_;          // 1024 f
  int*   topi  = (int*)(resc + 1024);           // 1024 i
  int*   pad   = topi + 1024;                   // 128 pad (keeps 16B align)
  short* w1h   = (short*)(pad + 128);           // 262144 sh
  short* w1l   = w1h + 2 * H_ * HFF_;
  short* w2h   = w1l + 2 * H_ * HFF_;
  short* w2l   = w2h + 2 * HFF_ * H_;
  short* wouth = w2l + 2 * HFF_ * H_;
  short* woutl = wouth + H_ * D_;

  k_h0<<<K_, 256, 0, stream>>>(cb, Win, bin, h0);
  k_uv<<<K_ + B_ * F_, 256, 0, stream>>>(h0, Wcat, bcat, xhat, u, v);
  k_wfrag<<<512, 256, 0, stream>>>(W1, w1h, w1l, HFF_, 32);
  k_wfrag<<<512, 256, 0, stream>>>(W1 + H_ * HFF_, w1h + H_ * HFF_, w1l + H_ * HFF_, HFF_, 32);
  k_wfrag<<<512, 256, 0, stream>>>(W2, w2h, w2l, H_, 16);
  k_wfrag<<<512, 256, 0, stream>>>(W2 + HFF_ * H_, w2h + HFF_ * H_, w2l + HFF_ * H_, H_, 16);
  k_wfrag<<<256, 256, 0, stream>>>(Wout, wouth, woutl, D_, 16);

  k_main<<<B_ * F_ * (K_ / RT), 256, 0, stream>>>(u, v, w1h, w1l, b1, w2h, w2l, b2,
                                                  wouth, woutl, bout, cb, xhat, x, dists);
  k_top8<<<B_, 256, 0, stream>>>(dists, topi);
  k_rescore<<<B_ * 8, 256, 0, stream>>>(u, v, W1, b1, W2, b2, Wout, bout, cb, xhat,
                                        x, topi, resc);
  k_final<<<B_, 256, 0, stream>>>(u, v, W1, b1, W2, b2, Wout, bout, cb, xhat,
                                  codes, topi, resc, out);
}